// Round 1
// baseline (540.932 us; speedup 1.0000x reference)
//
#include <hip/hip_runtime.h>
#include <cstdint>
#include <cstddef>

#define TT 4
#define BB 4
#define LL 1024
#define CC 256
#define HH 8
#define HD 32
#define NWIN 8
#define WIN 128
#define TOPKN 4
#define C3 768

// ---------------------------------------------------------------------------
// 1. region sums: region[b,n,c] = sum_t sum_r x[t,b,n*128+r,c]
//    (t summed innermost first, then rows ascending -> matches xs=x.sum(0) then .sum(axis=2))
__global__ __launch_bounds__(256) void region_kernel(const float* __restrict__ x,
                                                     float* __restrict__ region) {
    int bn = blockIdx.x;          // b*NWIN + n
    int b = bn >> 3, n = bn & 7;
    int c = threadIdx.x;
    float tot = 0.0f;
    for (int r = 0; r < WIN; ++r) {
        int l = n * WIN + r;
        float s = 0.0f;
        for (int t = 0; t < TT; ++t) {
            s += x[(((size_t)t * BB + b) * LL + l) * CC + c];
        }
        tot += s;
    }
    region[(size_t)bn * CC + c] = tot;
}

// ---------------------------------------------------------------------------
// 2. routing: attn_r[n,m] = dot(region[b,n], region[b,m]) * C^-0.5, top-4 per n
__global__ __launch_bounds__(64) void route_kernel(const float* __restrict__ region,
                                                   int* __restrict__ idx) {
    int b = blockIdx.x;
    __shared__ float reg[NWIN][CC];
    __shared__ float attn_r[NWIN][NWIN];
    int tid = threadIdx.x;
    for (int e = tid; e < NWIN * CC; e += 64)
        reg[e >> 8][e & 255] = region[(size_t)b * NWIN * CC + e];
    __syncthreads();
    int n = tid >> 3, m = tid & 7;
    float s = 0.0f;
    for (int c = 0; c < CC; ++c) s += reg[n][c] * reg[m][c];
    attn_r[n][m] = s * 0.0625f;   // C^-0.5 = 1/16 exact
    __syncthreads();
    if (tid < NWIN) {
        float vals[NWIN];
        for (int m2 = 0; m2 < NWIN; ++m2) vals[m2] = attn_r[tid][m2];
        for (int kk = 0; kk < TOPKN; ++kk) {
            int bi = 0; float bv = vals[0];
            for (int m2 = 1; m2 < NWIN; ++m2) {
                if (vals[m2] > bv) { bv = vals[m2]; bi = m2; }  // strict > : ties -> lower idx (lax.top_k)
            }
            idx[(b * NWIN + tid) * TOPKN + kk] = bi;
            vals[bi] = -INFINITY;
        }
    }
}

// ---------------------------------------------------------------------------
// 3. fp32 GEMM + bias: C[m,n] = sum_k A[m,k]*W[k,n] + bias[n]
//    BM=128 BN=64 BK=16, 256 threads, 8x4 micro-tile. K accumulated ascending (Eigen-like).
__global__ __launch_bounds__(256) void gemm_bias(const float* __restrict__ A,
                                                 const float* __restrict__ W,
                                                 const float* __restrict__ bias,
                                                 float* __restrict__ C,
                                                 int M, int N, int K) {
    const int BM = 128, BN = 64, BK = 16, TM = 8, TN = 4;
    __shared__ float As[BK][BM + 4];   // stride 132: 2-way max bank alias on store (free)
    __shared__ float Bs[BK][BN];
    int tid = threadIdx.x;
    int tx = tid & 15, ty = tid >> 4;
    int bm = blockIdx.x * BM, bn = blockIdx.y * BN;
    float acc[TM][TN] = {};
    for (int k0 = 0; k0 < K; k0 += BK) {
#pragma unroll
        for (int it = 0; it < 2; ++it) {
            int i = it * 256 + tid;
            int row = i >> 2, kc = (i & 3) * 4;
            float4 v = *(const float4*)(A + (size_t)(bm + row) * K + k0 + kc);
            As[kc + 0][row] = v.x; As[kc + 1][row] = v.y;
            As[kc + 2][row] = v.z; As[kc + 3][row] = v.w;
        }
        {
            int kr = tid >> 4, nc = (tid & 15) * 4;
            float4 v = *(const float4*)(W + (size_t)(k0 + kr) * N + bn + nc);
            *(float4*)&Bs[kr][nc] = v;
        }
        __syncthreads();
#pragma unroll
        for (int kk = 0; kk < BK; ++kk) {
            float a[TM], bb[TN];
            const float4* ap = (const float4*)&As[kk][ty * TM];
            float4 a0 = ap[0], a1 = ap[1];
            a[0]=a0.x; a[1]=a0.y; a[2]=a0.z; a[3]=a0.w;
            a[4]=a1.x; a[5]=a1.y; a[6]=a1.z; a[7]=a1.w;
            float4 b0 = *(const float4*)&Bs[kk][tx * TN];
            bb[0]=b0.x; bb[1]=b0.y; bb[2]=b0.z; bb[3]=b0.w;
#pragma unroll
            for (int i = 0; i < TM; ++i)
#pragma unroll
                for (int j = 0; j < TN; ++j)
                    acc[i][j] = fmaf(a[i], bb[j], acc[i][j]);
        }
        __syncthreads();
    }
#pragma unroll
    for (int i = 0; i < TM; ++i) {
        int row = bm + ty * TM + i;
#pragma unroll
        for (int j = 0; j < TN; ++j) {
            int col = bn + tx * TN + j;
            C[(size_t)row * N + col] = acc[i][j] + bias[col];
        }
    }
}

// ---------------------------------------------------------------------------
// 4. LIF over T (src may == dst for in-place). v=(v+x)/2 via v+(x-v)*0.5; spike v>=1; hard reset.
__global__ __launch_bounds__(256) void lif_kernel(const float* src, float* dst, size_t stride) {
    size_t i = ((size_t)blockIdx.x * blockDim.x + threadIdx.x) * 4;
    float v[4] = {0.f, 0.f, 0.f, 0.f};
    for (int t = 0; t < TT; ++t) {
        float4 xv4 = *(const float4*)(src + (size_t)t * stride + i);
        float xv[4] = {xv4.x, xv4.y, xv4.z, xv4.w};
        float sp[4];
#pragma unroll
        for (int j = 0; j < 4; ++j) {
            v[j] = v[j] + (xv[j] - v[j]) * 0.5f;   // fma contraction exact here (d*0.5 exact)
            bool fire = (v[j] >= 1.0f);
            sp[j] = fire ? 1.0f : 0.0f;
            v[j] = fire ? 0.0f : v[j];
        }
        *(float4*)(dst + (size_t)t * stride + i) = make_float4(sp[0], sp[1], sp[2], sp[3]);
    }
}

// ---------------------------------------------------------------------------
// 5. windowed spike attention. Block = (t,b,n,head-pair hp). 256 threads.
//    Spikes bit-packed (32 dims -> uint32); QK^T = popc (exact integer, == fp32 ref bitwise).
__global__ __launch_bounds__(256) void attn_kernel(const float* __restrict__ spk,
                                                   const int* __restrict__ idxws,
                                                   float* __restrict__ out) {
    int bid = blockIdx.x;
    int hp = bid & 3, n = (bid >> 2) & 7, b = (bid >> 5) & 3, t = bid >> 7;
    __shared__ uint32_t qb[WIN][2];
    __shared__ uint32_t kb[4 * WIN][2];
    __shared__ uint32_t vb[4 * WIN][2];
    __shared__ int sidx[TOPKN];
    int tid = threadIdx.x;
    int lane = tid & 63;
    if (tid < TOPKN) sidx[tid] = idxws[(b * NWIN + n) * TOPKN + tid];
    __syncthreads();
    size_t base = (((size_t)t * BB + b) * LL) * C3;
    // pack Q: 128 rows x 64 cols (this head pair)
    for (int e = tid; e < WIN * 64; e += 256) {
        int r = e >> 6, c = e & 63;
        float val = spk[base + (size_t)(n * WIN + r) * C3 + hp * 64 + c];
        unsigned long long m = __ballot(val >= 0.5f);
        if (lane == 0)  qb[r][0] = (uint32_t)m;
        if (lane == 32) qb[r][1] = (uint32_t)(m >> 32);
    }
    // pack gathered K and V: 512 rows x 64 cols
    for (int e = tid; e < 4 * WIN * 64; e += 256) {
        int r = e >> 6, c = e & 63;
        int lsrc = sidx[r >> 7] * WIN + (r & 127);
        size_t rowb = base + (size_t)lsrc * C3 + hp * 64 + c;
        float kvv = spk[rowb + 256];
        unsigned long long mk = __ballot(kvv >= 0.5f);
        if (lane == 0)  kb[r][0] = (uint32_t)mk;
        if (lane == 32) kb[r][1] = (uint32_t)(mk >> 32);
        float vvv = spk[rowb + 512];
        unsigned long long mv = __ballot(vvv >= 0.5f);
        if (lane == 0)  vb[r][0] = (uint32_t)mv;
        if (lane == 32) vb[r][1] = (uint32_t)(mv >> 32);
    }
    __syncthreads();

    const float ALPHA_SC = 0.17677669529663687f;   // hd^-0.5
    int h = tid & 1, q = tid >> 1;
    uint32_t qw = qb[q][h];
    // pass 1: integer max score (monotone -> matches ref fp32 max)
    int smax = 0;
    for (int k = 0; k < 4 * WIN; ++k) {
        int s = __popc(qw & kb[k][h]);
        smax = max(smax, s);
    }
    float am = __fmul_rn((float)smax, ALPHA_SC);
    // pass 2: softmax denominator (ascending k)
    float Z = 0.0f;
    for (int k = 0; k < 4 * WIN; ++k) {
        int s = __popc(qw & kb[k][h]);
        float a = __fmul_rn((float)s, ALPHA_SC);
        Z += expf(__fsub_rn(a, am));
    }
    // pass 3: P = e/Z per k, PV accumulate ascending k with bit-masked adds
    float acc[HD];
#pragma unroll
    for (int d = 0; d < HD; ++d) acc[d] = 0.0f;
    for (int k = 0; k < 4 * WIN; ++k) {
        int s = __popc(qw & kb[k][h]);
        float a = __fmul_rn((float)s, ALPHA_SC);
        float P = expf(__fsub_rn(a, am)) / Z;
        uint32_t vw = vb[k][h];
        uint32_t pbits = __float_as_uint(P);
#pragma unroll
        for (int d = 0; d < HD; ++d) {
            uint32_t msk = (uint32_t)(((int32_t)(vw << (31 - d))) >> 31);
            acc[d] += __uint_as_float(pbits & msk);
        }
    }
    size_t obase = ((((size_t)t * BB + b) * LL) + (size_t)n * WIN + q) * CC + (hp * 2 + h) * 32;
#pragma unroll
    for (int d = 0; d < HD; ++d) out[obase + d] = acc[d];
}

// ---------------------------------------------------------------------------
extern "C" void kernel_launch(void* const* d_in, const int* in_sizes, int n_in,
                              void* d_out, int out_size, void* d_ws, size_t ws_size,
                              hipStream_t stream) {
    const float* x      = (const float*)d_in[0];
    const float* w_qkv  = (const float*)d_in[1];
    const float* b_qkv  = (const float*)d_in[2];
    const float* w_proj = (const float*)d_in[3];
    const float* b_proj = (const float*)d_in[4];
    float* ws = (float*)d_ws;

    float* qkv      = ws;                 // 12582912 floats [T,B,L,3C] (becomes spikes in-place)
    float* attn_out = ws + 12582912;      // 4194304 floats [T,B,L,C]
    float* proj     = ws + 16777216;      // 4194304 floats [T,B,L,C]
    float* region   = ws + 20971520;      // 8192 floats [B,NWIN,C]
    int*   idxp     = (int*)(ws + 20979712);  // 128 ints [B,NWIN,TOPK]
    float* outp     = (float*)d_out;

    region_kernel<<<dim3(BB * NWIN), dim3(256), 0, stream>>>(x, region);
    route_kernel<<<dim3(BB), dim3(64), 0, stream>>>(region, idxp);
    gemm_bias<<<dim3(128, 12), dim3(256), 0, stream>>>(x, w_qkv, b_qkv, qkv,
                                                       TT * BB * LL, C3, CC);
    lif_kernel<<<dim3(3072), dim3(256), 0, stream>>>(qkv, qkv, (size_t)BB * LL * C3);
    attn_kernel<<<dim3(TT * BB * NWIN * 4), dim3(256), 0, stream>>>(qkv, idxp, attn_out);
    gemm_bias<<<dim3(128, 4), dim3(256), 0, stream>>>(attn_out, w_proj, b_proj, proj,
                                                      TT * BB * LL, CC, CC);
    lif_kernel<<<dim3(1024), dim3(256), 0, stream>>>(proj, outp, (size_t)BB * LL * CC);
}

// Round 3
// 427.540 us; speedup vs baseline: 1.2652x; 1.2652x over previous
//
#include <hip/hip_runtime.h>
#include <cstdint>
#include <cstddef>

#define TT 4
#define BB 4
#define LL 1024
#define CC 256
#define HH 8
#define HD 32
#define NWIN 8
#define WIN 128
#define TOPKN 4
#define C3 768

// ---------------------------------------------------------------------------
// 1. region sums: region[b,n,c] = sum_t sum_r x[t,b,n*128+r,c]
__global__ __launch_bounds__(256) void region_kernel(const float* __restrict__ x,
                                                     float* __restrict__ region) {
    int bn = blockIdx.x;          // b*NWIN + n
    int b = bn >> 3, n = bn & 7;
    int c = threadIdx.x;
    float tot = 0.0f;
    for (int r = 0; r < WIN; ++r) {
        int l = n * WIN + r;
        float s = 0.0f;
        for (int t = 0; t < TT; ++t) {
            s += x[(((size_t)t * BB + b) * LL + l) * CC + c];
        }
        tot += s;
    }
    region[(size_t)bn * CC + c] = tot;
}

// ---------------------------------------------------------------------------
// 2. routing: attn_r[n,m] = dot(region[b,n], region[b,m]) * C^-0.5, top-4 per n
__global__ __launch_bounds__(64) void route_kernel(const float* __restrict__ region,
                                                   int* __restrict__ idx) {
    int b = blockIdx.x;
    __shared__ float reg[NWIN][CC];
    __shared__ float attn_r[NWIN][NWIN];
    int tid = threadIdx.x;
    for (int e = tid; e < NWIN * CC; e += 64)
        reg[e >> 8][e & 255] = region[(size_t)b * NWIN * CC + e];
    __syncthreads();
    int n = tid >> 3, m = tid & 7;
    float s = 0.0f;
    for (int c = 0; c < CC; ++c) s += reg[n][c] * reg[m][c];
    attn_r[n][m] = s * 0.0625f;   // C^-0.5 = 1/16 exact
    __syncthreads();
    if (tid < NWIN) {
        float vals[NWIN];
        for (int m2 = 0; m2 < NWIN; ++m2) vals[m2] = attn_r[tid][m2];
        for (int kk = 0; kk < TOPKN; ++kk) {
            int bi = 0; float bv = vals[0];
            for (int m2 = 1; m2 < NWIN; ++m2) {
                if (vals[m2] > bv) { bv = vals[m2]; bi = m2; }
            }
            idx[(b * NWIN + tid) * TOPKN + kk] = bi;
            vals[bi] = -INFINITY;
        }
    }
}

// ---------------------------------------------------------------------------
// 3. fp32 GEMM + bias (K ascending, exact)
__global__ __launch_bounds__(256) void gemm_bias(const float* __restrict__ A,
                                                 const float* __restrict__ W,
                                                 const float* __restrict__ bias,
                                                 float* __restrict__ C,
                                                 int M, int N, int K) {
    const int BM = 128, BN = 64, BK = 16, TM = 8, TN = 4;
    __shared__ float As[BK][BM + 4];
    __shared__ float Bs[BK][BN];
    int tid = threadIdx.x;
    int tx = tid & 15, ty = tid >> 4;
    int bm = blockIdx.x * BM, bn = blockIdx.y * BN;
    float acc[TM][TN] = {};
    for (int k0 = 0; k0 < K; k0 += BK) {
#pragma unroll
        for (int it = 0; it < 2; ++it) {
            int i = it * 256 + tid;
            int row = i >> 2, kc = (i & 3) * 4;
            float4 v = *(const float4*)(A + (size_t)(bm + row) * K + k0 + kc);
            As[kc + 0][row] = v.x; As[kc + 1][row] = v.y;
            As[kc + 2][row] = v.z; As[kc + 3][row] = v.w;
        }
        {
            int kr = tid >> 4, nc = (tid & 15) * 4;
            float4 v = *(const float4*)(W + (size_t)(k0 + kr) * N + bn + nc);
            *(float4*)&Bs[kr][nc] = v;
        }
        __syncthreads();
#pragma unroll
        for (int kk = 0; kk < BK; ++kk) {
            float a[TM], bb[TN];
            const float4* ap = (const float4*)&As[kk][ty * TM];
            float4 a0 = ap[0], a1 = ap[1];
            a[0]=a0.x; a[1]=a0.y; a[2]=a0.z; a[3]=a0.w;
            a[4]=a1.x; a[5]=a1.y; a[6]=a1.z; a[7]=a1.w;
            float4 b0 = *(const float4*)&Bs[kk][tx * TN];
            bb[0]=b0.x; bb[1]=b0.y; bb[2]=b0.z; bb[3]=b0.w;
#pragma unroll
            for (int i = 0; i < TM; ++i)
#pragma unroll
                for (int j = 0; j < TN; ++j)
                    acc[i][j] = fmaf(a[i], bb[j], acc[i][j]);
        }
        __syncthreads();
    }
#pragma unroll
    for (int i = 0; i < TM; ++i) {
        int row = bm + ty * TM + i;
#pragma unroll
        for (int j = 0; j < TN; ++j) {
            int col = bn + tx * TN + j;
            C[(size_t)row * N + col] = acc[i][j] + bias[col];
        }
    }
}

// ---------------------------------------------------------------------------
// 4. LIF over T
__global__ __launch_bounds__(256) void lif_kernel(const float* src, float* dst, size_t stride) {
    size_t i = ((size_t)blockIdx.x * blockDim.x + threadIdx.x) * 4;
    float v[4] = {0.f, 0.f, 0.f, 0.f};
    for (int t = 0; t < TT; ++t) {
        float4 xv4 = *(const float4*)(src + (size_t)t * stride + i);
        float xv[4] = {xv4.x, xv4.y, xv4.z, xv4.w};
        float sp[4];
#pragma unroll
        for (int j = 0; j < 4; ++j) {
            v[j] = v[j] + (xv[j] - v[j]) * 0.5f;
            bool fire = (v[j] >= 1.0f);
            sp[j] = fire ? 1.0f : 0.0f;
            v[j] = fire ? 0.0f : v[j];
        }
        *(float4*)(dst + (size_t)t * stride + i) = make_float4(sp[0], sp[1], sp[2], sp[3]);
    }
}

// ---------------------------------------------------------------------------
// 4b. pack Q/K spike bits: pk[row][0..7] = q words, pk[row][8..15] = k words
__global__ __launch_bounds__(256) void pack_kernel(const float* __restrict__ spk,
                                                   uint32_t* __restrict__ pk) {
    size_t g = (size_t)blockIdx.x * 256 + threadIdx.x;   // over 16384*512
    int row = (int)(g >> 9);
    int col = (int)(g & 511);
    float v = spk[(size_t)row * C3 + col];
    unsigned long long m = __ballot(v >= 0.5f);
    int lane = threadIdx.x & 63;
    if ((lane & 31) == 0)
        pk[(size_t)row * 16 + (col >> 5)] = (lane < 32) ? (uint32_t)m : (uint32_t)(m >> 32);
}

// ---------------------------------------------------------------------------
// 5. windowed spike attention v2. Block = (t,b,n,hp), 256 threads:
//    q = tid&127, h = tid>>7 (wave-uniform h). P-table (33 values) in LDS;
//    PV via fmaf(P, v_float, acc); V rows wave-uniform, double-buffered in regs.
__device__ __forceinline__ const float4* vrowptr(const float* vbase, const int* sidx, int k) {
    int row = sidx[k >> 7] * WIN + (k & 127);
    return (const float4*)(vbase + (size_t)row * C3);
}

__global__ __launch_bounds__(256) void attn_kernel(const float* __restrict__ spk,
                                                   const uint32_t* __restrict__ pk,
                                                   const int* __restrict__ idxws,
                                                   float* __restrict__ out) {
    int bid = blockIdx.x;
    int hp = bid & 3, n = (bid >> 2) & 7, b = (bid >> 5) & 3, t = bid >> 7;
    __shared__ uint32_t kbs[2][512];
    __shared__ float ptab[33][256];
    __shared__ int sidx[TOPKN];
    int tid = threadIdx.x;
    int q = tid & 127, h = tid >> 7;
    int lbase = (t * BB + b) * LL;

    if (tid < TOPKN) sidx[tid] = idxws[(b * NWIN + n) * TOPKN + tid];
    __syncthreads();
    // stage gathered K bit-words (both halves)
    for (int e = tid; e < 1024; e += 256) {
        int hh = e >> 9, kk = e & 511;
        int row = sidx[kk >> 7] * WIN + (kk & 127);
        kbs[hh][kk] = pk[(size_t)(lbase + row) * 16 + 8 + hp * 2 + hh];
    }
    uint32_t qw = pk[(size_t)(lbase + n * WIN + q) * 16 + hp * 2 + h];
    __syncthreads();

    const float ALPHA_SC = 0.17677669529663687f;   // hd^-0.5
    // pass 1: integer max score
    int smax = 0;
    for (int k = 0; k < 512; ++k) smax = max(smax, __popc(qw & kbs[h][k]));
    float am = __fmul_rn((float)smax, ALPHA_SC);
    // pass 2: Z (ascending k, identical expression to reference path)
    float Z = 0.0f;
    for (int k = 0; k < 512; ++k) {
        int s = __popc(qw & kbs[h][k]);
        Z += expf(__fsub_rn(__fmul_rn((float)s, ALPHA_SC), am));
    }
    // per-thread P table (33 distinct values); own column only -> no barrier needed
    for (int s = 0; s <= 32; ++s)
        ptab[s][tid] = expf(__fsub_rn(__fmul_rn((float)s, ALPHA_SC), am)) / Z;

    // pass 3: PV with fp32 fma against raw spike floats (bitwise == add-or-skip)
    const float* vbase = spk + (size_t)lbase * C3 + 512 + hp * 64 + h * 32;
    float acc[32];
#pragma unroll
    for (int d = 0; d < 32; ++d) acc[d] = 0.0f;

    float4 Av[8], Bv[8];
    {
        const float4* p0 = vrowptr(vbase, sidx, 0);
#pragma unroll
        for (int j = 0; j < 8; ++j) Av[j] = p0[j];
    }
    for (int k = 0; k < 512; k += 2) {
        const float4* pb = vrowptr(vbase, sidx, k + 1);
#pragma unroll
        for (int j = 0; j < 8; ++j) Bv[j] = pb[j];
        {
            int s = __popc(qw & kbs[h][k]);
            float P = ptab[s][tid];
#pragma unroll
            for (int j = 0; j < 8; ++j) {
                acc[4*j+0] = fmaf(P, Av[j].x, acc[4*j+0]);
                acc[4*j+1] = fmaf(P, Av[j].y, acc[4*j+1]);
                acc[4*j+2] = fmaf(P, Av[j].z, acc[4*j+2]);
                acc[4*j+3] = fmaf(P, Av[j].w, acc[4*j+3]);
            }
        }
        const float4* pa = vrowptr(vbase, sidx, (k + 2) & 511);
#pragma unroll
        for (int j = 0; j < 8; ++j) Av[j] = pa[j];
        {
            int s = __popc(qw & kbs[h][k + 1]);
            float P = ptab[s][tid];
#pragma unroll
            for (int j = 0; j < 8; ++j) {
                acc[4*j+0] = fmaf(P, Bv[j].x, acc[4*j+0]);
                acc[4*j+1] = fmaf(P, Bv[j].y, acc[4*j+1]);
                acc[4*j+2] = fmaf(P, Bv[j].z, acc[4*j+2]);
                acc[4*j+3] = fmaf(P, Bv[j].w, acc[4*j+3]);
            }
        }
    }

    size_t obase = (size_t)(lbase + n * WIN + q) * CC + (hp * 2 + h) * 32;
#pragma unroll
    for (int d = 0; d < 32; ++d) out[obase + d] = acc[d];
}

// ---------------------------------------------------------------------------
extern "C" void kernel_launch(void* const* d_in, const int* in_sizes, int n_in,
                              void* d_out, int out_size, void* d_ws, size_t ws_size,
                              hipStream_t stream) {
    const float* x      = (const float*)d_in[0];
    const float* w_qkv  = (const float*)d_in[1];
    const float* b_qkv  = (const float*)d_in[2];
    const float* w_proj = (const float*)d_in[3];
    const float* b_proj = (const float*)d_in[4];
    float* ws = (float*)d_ws;

    float* qkv      = ws;                 // 12582912 floats [T,B,L,3C] (spikes after LIF)
    float* attn_out = ws + 12582912;      // 4194304 floats [T,B,L,C]
    float* proj     = ws + 16777216;      // 4194304 floats [T,B,L,C]
    uint32_t* pkb   = (uint32_t*)proj;    // 262144 u32: aliases proj (dead before gemm_proj)
    float* region   = ws + 20971520;      // 8192 floats
    int*   idxp     = (int*)(ws + 20979712);  // 128 ints
    float* outp     = (float*)d_out;

    region_kernel<<<dim3(BB * NWIN), dim3(256), 0, stream>>>(x, region);
    route_kernel<<<dim3(BB), dim3(64), 0, stream>>>(region, idxp);
    gemm_bias<<<dim3(128, 12), dim3(256), 0, stream>>>(x, w_qkv, b_qkv, qkv,
                                                       TT * BB * LL, C3, CC);
    lif_kernel<<<dim3(3072), dim3(256), 0, stream>>>(qkv, qkv, (size_t)BB * LL * C3);
    pack_kernel<<<dim3(32768), dim3(256), 0, stream>>>(qkv, pkb);
    attn_kernel<<<dim3(TT * BB * NWIN * 4), dim3(256), 0, stream>>>(qkv, pkb, idxp, attn_out);
    gemm_bias<<<dim3(128, 4), dim3(256), 0, stream>>>(attn_out, w_proj, b_proj, proj,
                                                      TT * BB * LL, CC, CC);
    lif_kernel<<<dim3(1024), dim3(256), 0, stream>>>(proj, outp, (size_t)BB * LL * CC);
}